// Round 16
// baseline (561.480 us; speedup 1.0000x reference)
//
#include <hip/hip_runtime.h>
#include <cstdint>
#include <cstddef>

#define NN     20000
#define NE     320000
#define NR     16
#define DIN    128
#define DH     512
#define DOUT   128
#define NT     50000
#define TILE   64                      // decode row tile
#define TILE1  128                     // layer-1 edge tile
#define CHUNKS 5
#define CHD    4000
#define NBUCKET (CHUNKS * NR)          // 80
#define MSGROWS 69888                  // max edges per chunk
#define MAXTPC1 2240                   // l1 grid per chunk (8*280)
#define NTILESMAX1 (NE / TILE1 + NBUCKET)
#define TMGRID ((NTILESMAX1 + 255) / 256)
#define MT2Y   157                     // ceil(20000/128)
#define YGRID  (MT2Y * 16)             // 2512 = 8*314
#define QGRID  320                     // 157*2=314 padded to %8

typedef __attribute__((ext_vector_type(8))) short bf16x8;
typedef __attribute__((ext_vector_type(4))) float f32x4;

__device__ __forceinline__ unsigned short f2bf(float x) {
    unsigned int b = __float_as_uint(x);
    b = b + 0x7fffu + ((b >> 16) & 1u);
    return (unsigned short)(b >> 16);
}
__device__ __forceinline__ float bf2f(unsigned short u) {
    return __uint_as_float(((unsigned int)u) << 16);
}
__device__ __forceinline__ unsigned packbf(float lo, float hi) {
    return (unsigned)f2bf(lo) | ((unsigned)f2bf(hi) << 16);
}

// ---------------- fused prep A: alpha1 (blocks 0..127) + alpha2 (128..191) ----------------
__global__ void prep_a_kernel(const float* __restrict__ W1, const float* __restrict__ aq1,
                              const float* __restrict__ ak1, float* __restrict__ alpha1,
                              const float* __restrict__ W2, const float* __restrict__ aq2,
                              const float* __restrict__ ak2, float* __restrict__ alpha2) {
    int bb = blockIdx.x;
    int c = threadIdx.x;
    if (bb < 128) {
        int i = bb;
        int r = c >> 4, s = (c >> 3) & 1, h = c & 7;
        const float* att = (s == 0 ? aq1 : ak1) + (r * 8 + h) * 64;
        const float* w = W1 + ((size_t)(r * DIN + i)) * DH + h * 64;
        float acc = 0.f;
        #pragma unroll 8
        for (int o = 0; o < 64; ++o) acc += w[o] * att[o];
        alpha1[i * 256 + c] = acc;
    } else {
        int g = (bb - 128) * 256 + c;
        if (g >= DH * 32) return;
        int i = g >> 5, cc = g & 31;
        int r = cc >> 1, s = cc & 1;
        const float* att = (s == 0 ? aq2 : ak2) + r * DOUT;
        const float* w = W2 + ((size_t)(r * DH + i)) * DOUT;
        float acc = 0.f;
        #pragma unroll 8
        for (int o = 0; o < DOUT; ++o) acc += w[o] * att[o];
        alpha2[i * 32 + cc] = acc;
    }
}

// ---------------- fused prep B: split_x | splitW1T | splitW2T | splitLw1 | splitA1T ----------------
#define PB_X   2500
#define PB_W1  (PB_X + 128)
#define PB_W2  (PB_W1 + 32)
#define PB_LW  (PB_W2 + 128)
#define PB_A1  (PB_LW + 128)
__global__ void prep_b_kernel(const float* __restrict__ x, unsigned short* __restrict__ xhi,
                              unsigned short* __restrict__ xlo,
                              const float* __restrict__ W1, unsigned short* __restrict__ W1Thi,
                              const float* __restrict__ W2, unsigned short* __restrict__ W2Thi,
                              const float* __restrict__ lw1, unsigned short* __restrict__ Lhi,
                              unsigned short* __restrict__ Llo,
                              const float* __restrict__ alpha1, unsigned short* __restrict__ A1Thi,
                              unsigned short* __restrict__ A1Tlo) {
    __shared__ float T[128 * 65];
    int bb = blockIdx.x;
    int tid = threadIdx.x;
    if (bb < PB_X) {
        int g = bb * 256 + tid;
        if (g >= NN * DIN / 4) return;
        float4 v = ((const float4*)x)[g];
        ushort4 h, l;
        h.x = f2bf(v.x); l.x = f2bf(v.x - bf2f(h.x));
        h.y = f2bf(v.y); l.y = f2bf(v.y - bf2f(h.y));
        h.z = f2bf(v.z); l.z = f2bf(v.z - bf2f(h.z));
        h.w = f2bf(v.w); l.w = f2bf(v.w - bf2f(h.w));
        ((ushort4*)xhi)[g] = h;
        ((ushort4*)xlo)[g] = l;
    } else if (bb < PB_W1) {
        int blk = bb - PB_X;
        int r = blk >> 3, ob = blk & 7;
        for (int idx = tid; idx < 128 * 64; idx += 256) {
            int i = idx >> 6, o = idx & 63;
            T[i * 65 + o] = W1[((size_t)(r * DIN + i)) * DH + ob * 64 + o];
        }
        __syncthreads();
        for (int idx = tid; idx < 64 * 128; idx += 256) {
            int o = idx >> 7, i = idx & 127;
            W1Thi[((size_t)r * DH + ob * 64 + o) * DIN + i] = f2bf(T[i * 65 + o]);
        }
    } else if (bb < PB_W2) {
        int blk = bb - PB_W1;
        int r = blk >> 1, ob = blk & 1;
        for (int kc = 0; kc < 4; ++kc) {
            if (kc) __syncthreads();
            for (int idx = tid; idx < 128 * 64; idx += 256) {
                int k = idx >> 6, o = idx & 63;
                T[k * 65 + o] = W2[((size_t)(r * DH + kc * 128 + k)) * DOUT + ob * 64 + o];
            }
            __syncthreads();
            for (int idx = tid; idx < 64 * 128; idx += 256) {
                int o = idx >> 7, k = idx & 127;
                W2Thi[((size_t)r * DOUT + ob * 64 + o) * DH + kc * 128 + k] = f2bf(T[k * 65 + o]);
            }
        }
    } else if (bb < PB_LW) {
        int g = (bb - PB_W2) * 256 + tid;
        if (g >= 256 * 128) return;
        int o = g >> 8, k = g & 255;
        float v = lw1[k * 128 + o];
        unsigned short h = f2bf(v);
        Lhi[(size_t)o * 256 + k] = h;
        Llo[(size_t)o * 256 + k] = f2bf(v - bf2f(h));
    } else {
        int g = (bb - PB_LW) * 256 + tid;
        if (g >= 128 * 256) return;
        int c = g >> 7, i = g & 127;
        float v = alpha1[i * 256 + c];
        unsigned short h = f2bf(v);
        A1Thi[g] = h;
        A1Tlo[g] = f2bf(v - bf2f(h));
    }
}

// ---------------- sorts ----------------
__global__ void hist_kernel(const int* __restrict__ ei, const int* __restrict__ et,
                            int* __restrict__ cnt, int* __restrict__ cnt_d) {
    __shared__ int bins[NBUCKET];
    int t = threadIdx.x;
    if (t < NBUCKET) bins[t] = 0;
    __syncthreads();
    int e = blockIdx.x * 256 + t;
    if (e < NE) {
        int d = ei[NE + e];
        int key = (d / CHD) * NR + et[e];
        atomicAdd(&bins[key], 1);
        atomicAdd(&cnt_d[d], 1);
    }
    __syncthreads();
    if (t < NBUCKET && bins[t]) atomicAdd(&cnt[t], bins[t]);
}

// fused: block 0 = bucket scan (thread 0), block 1 = dst scan (1024 threads)
__global__ void scan_fused_kernel(const int* __restrict__ cnt, int* __restrict__ boffs,
                                  int* __restrict__ cursor, int* __restrict__ cts,
                                  const int* __restrict__ cnt_d, int* __restrict__ doffs,
                                  int* __restrict__ cursor_d) {
    __shared__ int part[1024];
    int t = threadIdx.x;
    if (blockIdx.x == 0) {
        if (t != 0) return;
        int acc = 0, tiles = 0;
        for (int b = 0; b < NBUCKET; ++b) {
            if ((b & (NR - 1)) == 0) cts[b >> 4] = tiles;
            boffs[b] = acc; cursor[b] = acc;
            int cn = cnt[b];
            tiles += (cn + TILE1 - 1) / TILE1;
            acc += cn;
        }
        boffs[NBUCKET] = acc; cts[CHUNKS] = tiles;
    } else {
        int base = t * 20;
        int s = 0;
        for (int i = 0; i < 20 && base + i < NN; ++i) s += cnt_d[base + i];
        part[t] = s;
        __syncthreads();
        for (int off = 1; off < 1024; off <<= 1) {
            int v = (t >= off) ? part[t - off] : 0;
            __syncthreads();
            part[t] += v;
            __syncthreads();
        }
        int run = part[t] - s;
        for (int i = 0; i < 20 && base + i < NN; ++i) {
            doffs[base + i] = run; cursor_d[base + i] = run;
            run += cnt_d[base + i];
        }
        if (t == 1023) doffs[NN] = part[1023];
    }
}

// fused: blocks [0,TMGRID) = tilemap; rest = bucket_place
__global__ void tmbp_kernel(const int* __restrict__ boffs, int* __restrict__ tile_b,
                            int* __restrict__ tile_s, const int* __restrict__ ei,
                            const int* __restrict__ et, int* __restrict__ cursor,
                            int* __restrict__ border) {
    int tid = threadIdx.x;
    if (blockIdx.x < TMGRID) {
        __shared__ int bo[NBUCKET + 1];
        if (tid <= NBUCKET) bo[tid] = boffs[tid];
        __syncthreads();
        int t = blockIdx.x * 256 + tid;
        if (t >= NTILESMAX1) return;
        int acc = 0, bb = -1, ss = 0;
        for (int b = 0; b < NBUCKET; ++b) {
            int cn = bo[b + 1] - bo[b];
            int nt = (cn + TILE1 - 1) / TILE1;
            if (t >= acc && t < acc + nt) { bb = b; ss = bo[b] + (t - acc) * TILE1; }
            acc += nt;
        }
        tile_b[t] = bb; tile_s[t] = ss;
    } else {
        __shared__ int binc[NBUCKET], base_[NBUCKET], rank_[NBUCKET];
        if (tid < NBUCKET) { binc[tid] = 0; rank_[tid] = 0; }
        __syncthreads();
        int e = (blockIdx.x - TMGRID) * 256 + tid;
        int key = -1;
        if (e < NE) { key = (ei[NE + e] / CHD) * NR + et[e]; atomicAdd(&binc[key], 1); }
        __syncthreads();
        if (tid < NBUCKET && binc[tid]) base_[tid] = atomicAdd(&cursor[tid], binc[tid]);
        __syncthreads();
        if (key >= 0) border[base_[key] + atomicAdd(&rank_[key], 1)] = e;
    }
}

__global__ void place_dst_kernel(const int* __restrict__ border, const int* __restrict__ ei,
                                 const int* __restrict__ et, int* __restrict__ cursor_d,
                                 int* __restrict__ dlist, int* __restrict__ dedge,
                                 int* __restrict__ dsr) {
    int pos = blockIdx.x * 256 + threadIdx.x;
    if (pos >= NE) return;
    int e = border[pos];
    int d = ei[NE + e];
    int idx = atomicAdd(&cursor_d[d], 1);
    dlist[idx] = pos;
    dedge[idx] = e;
    dsr[idx] = ei[e] * NR + et[e];
}

// ---------------- qk1 = x @ alpha1 (MFMA, 3-term split bf16; full precision) ----------------
__global__ __launch_bounds__(256, 2)
void qk1_mfma_kernel(const unsigned short* __restrict__ xhi, const unsigned short* __restrict__ xlo,
                     const unsigned short* __restrict__ A1Thi, const unsigned short* __restrict__ A1Tlo,
                     float* __restrict__ qk1) {
    int t = (blockIdx.x & 7) * (QGRID / 8) + (blockIdx.x >> 3);
    if (t >= MT2Y * 2) return;
    int mt = t >> 1, nb = t & 1;
    int n0 = mt * 128;
    __shared__ __align__(16) unsigned short Ah[128 * 64];
    __shared__ __align__(16) unsigned short Al[128 * 64];
    __shared__ __align__(16) unsigned short Bh_[128 * 64];
    __shared__ __align__(16) unsigned short Bl_[128 * 64];
    int tid = threadIdx.x;
    int w = tid >> 6, lane = tid & 63;
    int l15 = lane & 15, l4 = lane >> 4;
    int wr = w >> 1, wc = w & 1;
    f32x4 acc[4][4];
    #pragma unroll
    for (int m = 0; m < 4; ++m)
        #pragma unroll
        for (int n = 0; n < 4; ++n) acc[m][n] = (f32x4){0.f, 0.f, 0.f, 0.f};
    for (int kc = 0; kc < 2; ++kc) {
        if (kc) __syncthreads();
        {
            int row = tid >> 1, seg = tid & 1;
            int n = n0 + row; if (n >= NN) n = NN - 1;
            unsigned rb = row * 128, sw = (row & 7) << 4;
            const uint4* ph = (const uint4*)(xhi + (size_t)n * DIN + kc * 64 + seg * 32);
            const uint4* pl = (const uint4*)(xlo + (size_t)n * DIN + kc * 64 + seg * 32);
            const uint4* qh = (const uint4*)(A1Thi + (size_t)(nb * 128 + row) * DIN + kc * 64 + seg * 32);
            const uint4* ql = (const uint4*)(A1Tlo + (size_t)(nb * 128 + row) * DIN + kc * 64 + seg * 32);
            #pragma unroll
            for (int i = 0; i < 4; ++i) {
                unsigned off = (rb + seg * 64 + i * 16) ^ sw;
                *(uint4*)((char*)Ah + off) = ph[i];
                *(uint4*)((char*)Al + off) = pl[i];
                *(uint4*)((char*)Bh_ + off) = qh[i];
                *(uint4*)((char*)Bl_ + off) = ql[i];
            }
        }
        __syncthreads();
        bf16x8 ah[4][2], al[4][2], bh[4][2], bl[4][2];
        #pragma unroll
        for (int m = 0; m < 4; ++m) {
            int row = wr * 64 + m * 16 + l15;
            unsigned rb = row * 128, sw = (row & 7) << 4;
            #pragma unroll
            for (int ks = 0; ks < 2; ++ks) {
                unsigned off = (rb + ks * 64 + l4 * 16) ^ sw;
                ah[m][ks] = *(const bf16x8*)((const char*)Ah + off);
                al[m][ks] = *(const bf16x8*)((const char*)Al + off);
            }
        }
        #pragma unroll
        for (int n = 0; n < 4; ++n) {
            int col = wc * 64 + n * 16 + l15;
            unsigned rb = col * 128, sw = (col & 7) << 4;
            #pragma unroll
            for (int ks = 0; ks < 2; ++ks) {
                unsigned off = (rb + ks * 64 + l4 * 16) ^ sw;
                bh[n][ks] = *(const bf16x8*)((const char*)Bh_ + off);
                bl[n][ks] = *(const bf16x8*)((const char*)Bl_ + off);
            }
        }
        #pragma unroll
        for (int n = 0; n < 4; ++n)
            #pragma unroll
            for (int ks = 0; ks < 2; ++ks)
                #pragma unroll
                for (int m = 0; m < 4; ++m) {
                    acc[m][n] = __builtin_amdgcn_mfma_f32_16x16x32_bf16(ah[m][ks], bh[n][ks], acc[m][n], 0, 0, 0);
                    acc[m][n] = __builtin_amdgcn_mfma_f32_16x16x32_bf16(al[m][ks], bh[n][ks], acc[m][n], 0, 0, 0);
                    acc[m][n] = __builtin_amdgcn_mfma_f32_16x16x32_bf16(ah[m][ks], bl[n][ks], acc[m][n], 0, 0, 0);
                }
    }
    #pragma unroll
    for (int m = 0; m < 4; ++m) {
        int row0 = n0 + wr * 64 + m * 16 + l4 * 4;
        #pragma unroll
        for (int rg = 0; rg < 4; ++rg) {
            int row = row0 + rg;
            if (row < NN) {
                float* op = qk1 + (size_t)row * 256 + nb * 128 + wc * 64 + l15;
                #pragma unroll
                for (int n = 0; n < 4; ++n) op[n * 16] = acc[m][n][rg];
            }
        }
    }
}

// elogit1 in dst-sorted position order: writes e1s[idx*8+h]
__global__ void elogit1_kernel(const int* __restrict__ dedge, const int* __restrict__ ei,
                               const int* __restrict__ et, const float* __restrict__ qk1,
                               float* __restrict__ e1s) {
    int idx = blockIdx.x * blockDim.x + threadIdx.x;
    if (idx >= NE) return;
    int e = dedge[idx];
    int src = ei[e], dst = ei[NE + e], r = et[e];
    const float* qp = qk1 + (size_t)dst * 256 + r * 16;
    const float* kp = qk1 + (size_t)src * 256 + r * 16 + 8;
    float* ep = e1s + (size_t)idx * 8;
    #pragma unroll
    for (int h = 0; h < 8; ++h) {
        float l = qp[h] + kp[h];
        l = l > 0.f ? l : 0.2f * l;
        ep[h] = __expf(l);
    }
}

// ---------------- layer1 GEMM: 128x128 tiles, pure bf16 ----------------
__global__ __launch_bounds__(256, 4)
void l1_gemm_kernel(const unsigned short* __restrict__ xhi,
                    const unsigned short* __restrict__ W1Thi,
                    const int* __restrict__ ei, const int* __restrict__ border,
                    const int* __restrict__ tile_b, const int* __restrict__ tile_s,
                    const int* __restrict__ boffs, const int* __restrict__ cts,
                    int c, unsigned* __restrict__ msgu) {
    int wg = (blockIdx.x & 7) * (MAXTPC1 / 8) + (blockIdx.x >> 3);
    int tt = wg >> 2, cb = wg & 3;
    int t = cts[c] + tt;
    if (t >= cts[c + 1]) return;
    int b = tile_b[t];
    int r = b & (NR - 1);
    int start = tile_s[t];
    int cstart = boffs[c * NR];
    int cnt = boffs[b + 1] - start; if (cnt > TILE1) cnt = TILE1;
    __shared__ __align__(16) unsigned short Ah[128 * 64];
    __shared__ __align__(16) unsigned short Bh_[128 * 64];
    __shared__ int srcS[TILE1];
    int tid = threadIdx.x;
    if (tid < TILE1) {
        int sv = 0;
        if (tid < cnt) sv = ei[border[start + tid]];
        srcS[tid] = sv;
    }
    __syncthreads();
    int w = tid >> 6, lane = tid & 63;
    int l15 = lane & 15, l4 = lane >> 4;
    int wr = w >> 1, wc = w & 1;
    f32x4 acc[4][4];
    #pragma unroll
    for (int m = 0; m < 4; ++m)
        #pragma unroll
        for (int n = 0; n < 4; ++n) acc[m][n] = (f32x4){0.f, 0.f, 0.f, 0.f};
    for (int kc = 0; kc < 2; ++kc) {
        if (kc) __syncthreads();
        {
            int row = tid >> 1, seg = tid & 1;
            unsigned rb = row * 128, sw = (row & 7) << 4;
            const uint4* ph = (const uint4*)(xhi + (size_t)srcS[row] * DIN + kc * 64 + seg * 32);
            const uint4* qh = (const uint4*)(W1Thi + ((size_t)r * DH + cb * 128 + row) * DIN + kc * 64 + seg * 32);
            #pragma unroll
            for (int i = 0; i < 4; ++i) {
                unsigned off = (rb + seg * 64 + i * 16) ^ sw;
                *(uint4*)((char*)Ah + off) = ph[i];
                *(uint4*)((char*)Bh_ + off) = qh[i];
            }
        }
        __syncthreads();
        bf16x8 ah[4][2], bh[4][2];
        #pragma unroll
        for (int m = 0; m < 4; ++m) {
            int row = wr * 64 + m * 16 + l15;
            unsigned rb = row * 128, sw = (row & 7) << 4;
            #pragma unroll
            for (int ks = 0; ks < 2; ++ks) {
                unsigned off = (rb + ks * 64 + l4 * 16) ^ sw;
                ah[m][ks] = *(const bf16x8*)((const char*)Ah + off);
            }
        }
        #pragma unroll
        for (int n = 0; n < 4; ++n) {
            int col = wc * 64 + n * 16 + l15;
            unsigned rb = col * 128, sw = (col & 7) << 4;
            #pragma unroll
            for (int ks = 0; ks < 2; ++ks) {
                unsigned off = (rb + ks * 64 + l4 * 16) ^ sw;
                bh[n][ks] = *(const bf16x8*)((const char*)Bh_ + off);
            }
        }
        #pragma unroll
        for (int n = 0; n < 4; ++n)
            #pragma unroll
            for (int ks = 0; ks < 2; ++ks)
                #pragma unroll
                for (int m = 0; m < 4; ++m)
                    acc[m][n] = __builtin_amdgcn_mfma_f32_16x16x32_bf16(ah[m][ks], bh[n][ks], acc[m][n], 0, 0, 0);
    }
    unsigned* mb = msgu + (size_t)(start - cstart) * 256 + cb * 64 + wc * 32 + l15;
    #pragma unroll
    for (int m = 0; m < 4; ++m) {
        int row0 = wr * 64 + m * 16 + l4 * 4;
        #pragma unroll
        for (int rg = 0; rg < 4; ++rg) {
            int row = row0 + rg;
            if (row < cnt) {
                unsigned* mp = mb + (size_t)row * 256;
                mp[0]  = packbf(acc[m][0][rg], acc[m][2][rg]);
                mp[16] = packbf(acc[m][1][rg], acc[m][3][rg]);
            }
        }
    }
}

// ---------------- layer1 agg (fused qk2): position-ordered weights, no indirection ----------------
__global__ void l1_agg_kernel(const unsigned* __restrict__ msgu, const float* __restrict__ e1s,
                              const int* __restrict__ dlist,
                              const int* __restrict__ doffs, const int* __restrict__ boffs,
                              int c, unsigned short* __restrict__ hhi,
                              const float* __restrict__ alpha2, float* __restrict__ qk2v) {
    __shared__ float hrow[DH];
    __shared__ float red[32][9];
    int tid = threadIdx.x;
    int d = c * CHD + blockIdx.x;
    if (d >= NN) return;
    int lo_ = doffs[d], hi_ = doffs[d + 1];
    int cstart = boffs[c * NR];
    int head = tid >> 5;
    float a0 = 0.f, a1 = 0.f, se = 0.f;
    int p = lo_;
    for (; p + 1 < hi_; p += 2) {
        int pos0 = dlist[p], pos1 = dlist[p + 1];
        float w0 = e1s[(size_t)p * 8 + head];
        float w1 = e1s[(size_t)(p + 1) * 8 + head];
        unsigned v0 = msgu[(size_t)(pos0 - cstart) * 256 + tid];
        unsigned v1 = msgu[(size_t)(pos1 - cstart) * 256 + tid];
        se += w0 + w1;
        a0 += w0 * bf2f((unsigned short)(v0 & 0xffff)) + w1 * bf2f((unsigned short)(v1 & 0xffff));
        a1 += w0 * bf2f((unsigned short)(v0 >> 16)) + w1 * bf2f((unsigned short)(v1 >> 16));
    }
    if (p < hi_) {
        int pos0 = dlist[p];
        float w0 = e1s[(size_t)p * 8 + head];
        unsigned v0 = msgu[(size_t)(pos0 - cstart) * 256 + tid];
        se += w0;
        a0 += w0 * bf2f((unsigned short)(v0 & 0xffff));
        a1 += w0 * bf2f((unsigned short)(v0 >> 16));
    }
    float inv = 1.f / (se + 1e-16f);
    a0 *= inv; a1 *= inv;
    a0 = a0 > 0.f ? a0 : 0.f;
    a1 = a1 > 0.f ? a1 : 0.f;
    int w = tid >> 6, q = (tid >> 4) & 3, l15 = tid & 15;
    int nq = ((q >> 1) << 2) | (q & 1);
    int c0 = w * 128 + nq * 16 + l15;
    hrow[c0] = a0; hrow[c0 + 32] = a1;
    hhi[(size_t)d * DH + c0] = f2bf(a0);
    hhi[(size_t)d * DH + c0 + 32] = f2bf(a1);
    __syncthreads();
    int j = tid & 31, ib = tid >> 5;
    float s = 0.f;
    #pragma unroll 8
    for (int i = ib * 64; i < ib * 64 + 64; ++i) s += hrow[i] * alpha2[(size_t)i * 32 + j];
    red[j][ib] = s;
    __syncthreads();
    if (tid < 32) {
        float t = 0.f;
        #pragma unroll
        for (int g = 0; g < 8; ++g) t += red[tid][g];
        qk2v[(size_t)d * 32 + tid] = t;
    }
}

// elogit2 in dst-sorted position order: writes e2s[idx]
__global__ void elogit2_kernel(const int* __restrict__ dedge, const int* __restrict__ ei,
                               const int* __restrict__ et, const float* __restrict__ qk2,
                               float* __restrict__ e2s) {
    int idx = blockIdx.x * blockDim.x + threadIdx.x;
    if (idx >= NE) return;
    int e = dedge[idx];
    int src = ei[e], dst = ei[NE + e], r = et[e];
    float l = qk2[(size_t)dst * 32 + r * 2] + qk2[(size_t)src * 32 + r * 2 + 1];
    l = l > 0.f ? l : 0.2f * l;
    e2s[idx] = __expf(l);
}

// ---------------- dense Y2 = H @ W2_all : pure bf16 ----------------
__global__ __launch_bounds__(256, 4)
void y2_gemm_kernel(const unsigned short* __restrict__ hhi,
                    const unsigned short* __restrict__ W2Thi,
                    unsigned* __restrict__ Y2u) {
    int t = (blockIdx.x & 7) * (YGRID / 8) + (blockIdx.x >> 3);
    int mt = t >> 4, r = t & 15;
    int n0 = mt * 128;
    __shared__ __align__(16) unsigned short Ah[128 * 64];
    __shared__ __align__(16) unsigned short Bh_[128 * 64];
    int tid = threadIdx.x;
    int w = tid >> 6, lane = tid & 63;
    int l15 = lane & 15, l4 = lane >> 4;
    int wr = w >> 1, wc = w & 1;
    f32x4 acc[4][4];
    #pragma unroll
    for (int m = 0; m < 4; ++m)
        #pragma unroll
        for (int n = 0; n < 4; ++n) acc[m][n] = (f32x4){0.f, 0.f, 0.f, 0.f};
    for (int kc = 0; kc < 8; ++kc) {
        if (kc) __syncthreads();
        {
            int row = tid >> 1, seg = tid & 1;
            int n = n0 + row; if (n >= NN) n = NN - 1;
            unsigned rb = row * 128, sw = (row & 7) << 4;
            const uint4* ph = (const uint4*)(hhi + (size_t)n * DH + kc * 64 + seg * 32);
            const uint4* qh = (const uint4*)(W2Thi + ((size_t)r * DOUT + row) * DH + kc * 64 + seg * 32);
            #pragma unroll
            for (int i = 0; i < 4; ++i) {
                unsigned off = (rb + seg * 64 + i * 16) ^ sw;
                *(uint4*)((char*)Ah + off) = ph[i];
                *(uint4*)((char*)Bh_ + off) = qh[i];
            }
        }
        __syncthreads();
        bf16x8 ah[4][2], bh[4][2];
        #pragma unroll
        for (int m = 0; m < 4; ++m) {
            int row = wr * 64 + m * 16 + l15;
            unsigned rb = row * 128, sw = (row & 7) << 4;
            #pragma unroll
            for (int ks = 0; ks < 2; ++ks) {
                unsigned off = (rb + ks * 64 + l4 * 16) ^ sw;
                ah[m][ks] = *(const bf16x8*)((const char*)Ah + off);
            }
        }
        #pragma unroll
        for (int n = 0; n < 4; ++n) {
            int col = wc * 64 + n * 16 + l15;
            unsigned rb = col * 128, sw = (col & 7) << 4;
            #pragma unroll
            for (int ks = 0; ks < 2; ++ks) {
                unsigned off = (rb + ks * 64 + l4 * 16) ^ sw;
                bh[n][ks] = *(const bf16x8*)((const char*)Bh_ + off);
            }
        }
        #pragma unroll
        for (int n = 0; n < 4; ++n)
            #pragma unroll
            for (int ks = 0; ks < 2; ++ks)
                #pragma unroll
                for (int m = 0; m < 4; ++m)
                    acc[m][n] = __builtin_amdgcn_mfma_f32_16x16x32_bf16(ah[m][ks], bh[n][ks], acc[m][n], 0, 0, 0);
    }
    unsigned* mb = Y2u + (size_t)n0 * 1024 + r * 64 + wc * 32 + l15;
    #pragma unroll
    for (int m = 0; m < 4; ++m) {
        int row0 = wr * 64 + m * 16 + l4 * 4;
        #pragma unroll
        for (int rg = 0; rg < 4; ++rg) {
            int row = row0 + rg;
            if (n0 + row < NN) {
                unsigned* mp = mb + (size_t)row * 1024;
                mp[0]  = packbf(acc[m][0][rg], acc[m][2][rg]);
                mp[16] = packbf(acc[m][1][rg], acc[m][3][rg]);
            }
        }
    }
}

// ---------------- layer2 agg: position-ordered weights, unrolled ----------------
__global__ void l2_agg_kernel(const unsigned* __restrict__ Y2u, const float* __restrict__ e2s,
                              const int* __restrict__ dsr,
                              const int* __restrict__ doffs, float* __restrict__ zacc) {
    int tid = threadIdx.x;
    int d = blockIdx.x * 4 + (tid >> 6);
    if (d >= NN) return;
    int lane = tid & 63;
    int lo_ = doffs[d], hi_ = doffs[d + 1];
    float a0 = 0.f, a1 = 0.f, se = 0.f;
    int p = lo_;
    for (; p + 1 < hi_; p += 2) {
        int s0 = dsr[p], s1 = dsr[p + 1];
        float w0 = e2s[p], w1 = e2s[p + 1];
        unsigned v0 = Y2u[(size_t)s0 * 64 + lane];
        unsigned v1 = Y2u[(size_t)s1 * 64 + lane];
        se += w0 + w1;
        a0 += w0 * bf2f((unsigned short)(v0 & 0xffff)) + w1 * bf2f((unsigned short)(v1 & 0xffff));
        a1 += w0 * bf2f((unsigned short)(v0 >> 16)) + w1 * bf2f((unsigned short)(v1 >> 16));
    }
    if (p < hi_) {
        float w0 = e2s[p];
        unsigned v0 = Y2u[(size_t)dsr[p] * 64 + lane];
        se += w0;
        a0 += w0 * bf2f((unsigned short)(v0 & 0xffff));
        a1 += w0 * bf2f((unsigned short)(v0 >> 16));
    }
    float inv = 1.f / (se + 1e-16f);
    int q = lane >> 4, l15 = lane & 15;
    int nq = ((q >> 1) << 2) | (q & 1);
    int c0 = nq * 16 + l15;
    zacc[(size_t)d * DOUT + c0] = a0 * inv;
    zacc[(size_t)d * DOUT + c0 + 32] = a1 * inv;
}

// ---------------- link-prediction decoder (MFMA, split bf16, full 3-term) ----------------
__global__ __launch_bounds__(256, 2)
void decode_kernel(const float* __restrict__ z, const int* __restrict__ tgt,
                   const unsigned short* __restrict__ Lhi, const unsigned short* __restrict__ Llo,
                   const float* __restrict__ lb1, const float* __restrict__ lw2,
                   const float* __restrict__ lb2, float* __restrict__ out) {
    __shared__ __align__(16) unsigned short Ah[64 * 256];
    __shared__ __align__(16) unsigned short Al[64 * 256];
    __shared__ float red[TILE][5];
    int t0 = blockIdx.x * TILE;
    int tid = threadIdx.x;
    int cnt = NT - t0; if (cnt > TILE) cnt = TILE;
    {
        int row = tid >> 2, seg = tid & 3;
        int node = 0;
        bool live = (row < cnt);
        if (live) node = tgt[(seg >> 1) * NT + t0 + row];
        const float4* pz = (const float4*)(z + (size_t)node * DOUT + (seg & 1) * 64);
        unsigned rb = row * 512, sb = (seg >> 1) * 256 + (seg & 1) * 128;
        unsigned sw = (row & 7) << 4;
        #pragma unroll
        for (int g = 0; g < 8; ++g) {
            float4 a = live ? pz[g * 2] : (float4){0,0,0,0};
            float4 bq = live ? pz[g * 2 + 1] : (float4){0,0,0,0};
            unsigned short h0 = f2bf(a.x), h1 = f2bf(a.y), h2 = f2bf(a.z), h3 = f2bf(a.w);
            unsigned short h4 = f2bf(bq.x), h5 = f2bf(bq.y), h6 = f2bf(bq.z), h7 = f2bf(bq.w);
            uint4 uh, ul;
            uh.x = (unsigned)h0 | ((unsigned)h1 << 16);
            uh.y = (unsigned)h2 | ((unsigned)h3 << 16);
            uh.z = (unsigned)h4 | ((unsigned)h5 << 16);
            uh.w = (unsigned)h6 | ((unsigned)h7 << 16);
            ul.x = (unsigned)f2bf(a.x - bf2f(h0)) | ((unsigned)f2bf(a.y - bf2f(h1)) << 16);
            ul.y = (unsigned)f2bf(a.z - bf2f(h2)) | ((unsigned)f2bf(a.w - bf2f(h3)) << 16);
            ul.z = (unsigned)f2bf(bq.x - bf2f(h4)) | ((unsigned)f2bf(bq.y - bf2f(h5)) << 16);
            ul.w = (unsigned)f2bf(bq.z - bf2f(h6)) | ((unsigned)f2bf(bq.w - bf2f(h7)) << 16);
            unsigned off = (rb + sb + g * 16) ^ sw;
            *(uint4*)((char*)Ah + off) = uh;
            *(uint4*)((char*)Al + off) = ul;
        }
    }
    __syncthreads();
    int w = tid >> 6, lane = tid & 63;
    int l15 = lane & 15, l4 = lane >> 4;
    const unsigned short* Bh = Lhi + (size_t)(w * 32 + l15) * 256 + l4 * 8;
    const unsigned short* Bl = Llo + (size_t)(w * 32 + l15) * 256 + l4 * 8;
    f32x4 acc[4][2];
    #pragma unroll
    for (int m = 0; m < 4; ++m) { acc[m][0] = (f32x4){0.f,0.f,0.f,0.f}; acc[m][1] = (f32x4){0.f,0.f,0.f,0.f}; }
    #pragma unroll
    for (int k = 0; k < 8; ++k) {
        bf16x8 ah[4], al[4];
        #pragma unroll
        for (int m = 0; m < 4; ++m) {
            int row = m * 16 + l15;
            unsigned off = ((unsigned)row * 512 + k * 64 + l4 * 16) ^ ((unsigned)(row & 7) << 4);
            ah[m] = *(const bf16x8*)((const char*)Ah + off);
            al[m] = *(const bf16x8*)((const char*)Al + off);
        }
        #pragma unroll
        for (int n = 0; n < 2; ++n) {
            bf16x8 bh = *(const bf16x8*)(Bh + (size_t)n * 16 * 256 + k * 32);
            bf16x8 bl = *(const bf16x8*)(Bl + (size_t)n * 16 * 256 + k * 32);
            #pragma unroll
            for (int m = 0; m < 4; ++m) {
                acc[m][n] = __builtin_amdgcn_mfma_f32_16x16x32_bf16(ah[m], bh, acc[m][n], 0, 0, 0);
                acc[m][n] = __builtin_amdgcn_mfma_f32_16x16x32_bf16(ah[m], bl, acc[m][n], 0, 0, 0);
                acc[m][n] = __builtin_amdgcn_mfma_f32_16x16x32_bf16(al[m], bh, acc[m][n], 0, 0, 0);
            }
        }
    }
    int col0 = w * 32 + l15;
    float lb_0 = lb1[col0], lb_1 = lb1[col0 + 16];
    float lwa = lw2[col0], lwb = lw2[col0 + 16];
    #pragma unroll
    for (int m = 0; m < 4; ++m) {
        #pragma unroll
        for (int rg = 0; rg < 4; ++rg) {
            float h0 = acc[m][0][rg] + lb_0; h0 = h0 > 0.f ? h0 : 0.f;
            float h1 = acc[m][1][rg] + lb_1; h1 = h1 > 0.f ? h1 : 0.f;
            float s = h0 * lwa + h1 * lwb;
            s += __shfl_xor(s, 1); s += __shfl_xor(s, 2);
            s += __shfl_xor(s, 4); s += __shfl_xor(s, 8);
            if (l15 == 0) red[m * 16 + l4 * 4 + rg][w] = s;
        }
    }
    __syncthreads();
    if (tid < cnt) out[t0 + tid] = red[tid][0] + red[tid][1] + red[tid][2] + red[tid][3] + lb2[0];
}

extern "C" void kernel_launch(void* const* d_in, const int* in_sizes, int n_in,
                              void* d_out, int out_size, void* d_ws, size_t ws_size,
                              hipStream_t stream) {
    const float* x   = (const float*)d_in[0];
    const int*   ei  = (const int*)d_in[1];
    const int*   et  = (const int*)d_in[2];
    const int*   tgt = (const int*)d_in[3];
    const float* W1  = (const float*)d_in[4];
    const float* aq1 = (const float*)d_in[5];
    const float* ak1 = (const float*)d_in[6];
    const float* W2  = (const float*)d_in[7];
    const float* aq2 = (const float*)d_in[8];
    const float* ak2 = (const float*)d_in[9];
    const float* lw1 = (const float*)d_in[10];
    const float* lb1 = (const float*)d_in[11];
    const float* lw2 = (const float*)d_in[12];
    const float* lb2 = (const float*)d_in[13];
    float* out = (float*)d_out;
    (void)in_sizes; (void)n_in; (void)out_size; (void)ws_size;

    char* ws = (char*)d_ws;
    size_t off = 0;
    auto alloc = [&](size_t bytes) -> void* {
        void* p = ws + off;
        off += (bytes + 255) & ~(size_t)255;
        return p;
    };
    // zero-init block: histograms only
    int* cnt   = (int*)alloc(NBUCKET * sizeof(int));
    int* cnt_d = (int*)alloc((size_t)NN * sizeof(int));
    size_t zero_bytes = off;
    // no-init scratch
    int*   boffs    = (int*)alloc((NBUCKET + 1) * sizeof(int));
    int*   cursor   = (int*)alloc(NBUCKET * sizeof(int));
    int*   cts      = (int*)alloc((CHUNKS + 1) * sizeof(int));
    int*   doffs    = (int*)alloc((size_t)(NN + 1) * sizeof(int));
    int*   cursor_d = (int*)alloc((size_t)NN * sizeof(int));
    int*   border   = (int*)alloc((size_t)NE * sizeof(int));
    int*   dlist    = (int*)alloc((size_t)NE * sizeof(int));
    int*   dedge    = (int*)alloc((size_t)NE * sizeof(int));
    int*   dsr      = (int*)alloc((size_t)NE * sizeof(int));
    int*   tile_b   = (int*)alloc((size_t)NTILESMAX1 * sizeof(int));
    int*   tile_s   = (int*)alloc((size_t)NTILESMAX1 * sizeof(int));
    float* alpha2   = (float*)alloc((size_t)512 * 32 * 4);
    float* qk2v     = (float*)alloc((size_t)NN * 32 * 4);
    float* e2s      = (float*)alloc((size_t)NE * 4);
    float* zacc     = (float*)alloc((size_t)NN * DOUT * 4);
    unsigned short* xhi   = (unsigned short*)alloc((size_t)NN * DIN * 2);
    unsigned short* xlo   = (unsigned short*)alloc((size_t)NN * DIN * 2);
    unsigned short* hhi   = (unsigned short*)alloc((size_t)NN * DH * 2);
    unsigned short* W1Thi = (unsigned short*)alloc((size_t)NR * DH * DIN * 2);
    unsigned short* W2Thi = (unsigned short*)alloc((size_t)NR * DOUT * DH * 2);
    unsigned short* Lhi   = (unsigned short*)alloc((size_t)128 * 256 * 2);
    unsigned short* Llo   = (unsigned short*)alloc((size_t)128 * 256 * 2);
    unsigned short* A1Thi = (unsigned short*)alloc((size_t)256 * 128 * 2);
    unsigned short* A1Tlo = (unsigned short*)alloc((size_t)256 * 128 * 2);
    // region R (82 MB): [alpha1|qk1] alias the head (dead before chunk-0 gemm);
    // msg occupies rows [0, MSGROWS); e1s sits at the fixed tail offset.
    // After the l1 loop the whole region is reused as the dense Y2 table.
    char* msgr = (char*)alloc((size_t)NN * 1024 * 4);               // 81,920,000 B
    unsigned* msgu = (unsigned*)msgr;
    unsigned* Y2u  = (unsigned*)msgr;
    float* alpha1 = (float*)msgr;                                   // 131,072 B
    float* qk1    = (float*)(msgr + 131072);                        // 20,480,000 B
    float* e1s    = (float*)(msgr + (size_t)MSGROWS * 1024);        // 10,240,000 B, ends 81.8 MB

    hipMemsetAsync(ws, 0, zero_bytes, stream);
    prep_a_kernel<<<192, 256, 0, stream>>>(W1, aq1, ak1, alpha1, W2, aq2, ak2, alpha2);
    prep_b_kernel<<<PB_A1 + 128, 256, 0, stream>>>(x, xhi, xlo, W1, W1Thi, W2, W2Thi,
                                                   lw1, Lhi, Llo, alpha1, A1Thi, A1Tlo);
    hist_kernel<<<(NE + 255) / 256, 256, 0, stream>>>(ei, et, cnt, cnt_d);
    scan_fused_kernel<<<2, 1024, 0, stream>>>(cnt, boffs, cursor, cts, cnt_d, doffs, cursor_d);
    tmbp_kernel<<<TMGRID + (NE + 255) / 256, 256, 0, stream>>>(boffs, tile_b, tile_s,
                                                               ei, et, cursor, border);
    place_dst_kernel<<<(NE + 255) / 256, 256, 0, stream>>>(border, ei, et, cursor_d, dlist, dedge, dsr);
    qk1_mfma_kernel<<<QGRID, 256, 0, stream>>>(xhi, xlo, A1Thi, A1Tlo, qk1);
    elogit1_kernel<<<(NE + 255) / 256, 256, 0, stream>>>(dedge, ei, et, qk1, e1s);
    for (int c = 0; c < CHUNKS; ++c) {
        l1_gemm_kernel<<<MAXTPC1, 256, 0, stream>>>(xhi, W1Thi, ei, border,
                                                    tile_b, tile_s, boffs, cts, c, msgu);
        l1_agg_kernel<<<CHD, 256, 0, stream>>>(msgu, e1s, dlist, doffs, boffs, c,
                                               hhi, alpha2, qk2v);
    }
    elogit2_kernel<<<(NE + 255) / 256, 256, 0, stream>>>(dedge, ei, et, qk2v, e2s);
    y2_gemm_kernel<<<YGRID, 256, 0, stream>>>(hhi, W2Thi, Y2u);
    l2_agg_kernel<<<(NN + 3) / 4, 256, 0, stream>>>(Y2u, e2s, dsr, doffs, zacc);
    decode_kernel<<<(NT + TILE - 1) / TILE, 256, 0, stream>>>(zacc, tgt, Lhi, Llo,
                                                              lb1, lw2, lb2, out);
}

// Round 17
// 550.193 us; speedup vs baseline: 1.0205x; 1.0205x over previous
//
#include <hip/hip_runtime.h>
#include <cstdint>
#include <cstddef>

#define NN     20000
#define NE     320000
#define NR     16
#define DIN    128
#define DH     512
#define DOUT   128
#define NT     50000
#define TILE   64                      // decode row tile
#define TILE1  128                     // layer-1 edge tile
#define CHUNKS 5
#define CHD    4000
#define NBUCKET (CHUNKS * NR)          // 80
#define MSGROWS 69888                  // max edges per chunk
#define MAXTPC1 2240                   // l1 grid per chunk (8*280)
#define NTILESMAX1 (NE / TILE1 + NBUCKET)
#define TMGRID ((NTILESMAX1 + 255) / 256)
#define MT2Y   157                     // ceil(20000/128)
#define YGRID  (MT2Y * 16)             // 2512 = 8*314
#define QGRID  320                     // 157*2=314 padded to %8

typedef __attribute__((ext_vector_type(8))) short bf16x8;
typedef __attribute__((ext_vector_type(4))) float f32x4;

__device__ __forceinline__ unsigned short f2bf(float x) {
    unsigned int b = __float_as_uint(x);
    b = b + 0x7fffu + ((b >> 16) & 1u);
    return (unsigned short)(b >> 16);
}
__device__ __forceinline__ float bf2f(unsigned short u) {
    return __uint_as_float(((unsigned int)u) << 16);
}
__device__ __forceinline__ unsigned packbf(float lo, float hi) {
    return (unsigned)f2bf(lo) | ((unsigned)f2bf(hi) << 16);
}

// ---------------- fused prep A: alpha1 (blocks 0..127) + alpha2 (128..191) ----------------
__global__ void prep_a_kernel(const float* __restrict__ W1, const float* __restrict__ aq1,
                              const float* __restrict__ ak1, float* __restrict__ alpha1,
                              const float* __restrict__ W2, const float* __restrict__ aq2,
                              const float* __restrict__ ak2, float* __restrict__ alpha2) {
    int bb = blockIdx.x;
    int c = threadIdx.x;
    if (bb < 128) {
        int i = bb;
        int r = c >> 4, s = (c >> 3) & 1, h = c & 7;
        const float* att = (s == 0 ? aq1 : ak1) + (r * 8 + h) * 64;
        const float* w = W1 + ((size_t)(r * DIN + i)) * DH + h * 64;
        float acc = 0.f;
        #pragma unroll 8
        for (int o = 0; o < 64; ++o) acc += w[o] * att[o];
        alpha1[i * 256 + c] = acc;
    } else {
        int g = (bb - 128) * 256 + c;
        if (g >= DH * 32) return;
        int i = g >> 5, cc = g & 31;
        int r = cc >> 1, s = cc & 1;
        const float* att = (s == 0 ? aq2 : ak2) + r * DOUT;
        const float* w = W2 + ((size_t)(r * DH + i)) * DOUT;
        float acc = 0.f;
        #pragma unroll 8
        for (int o = 0; o < DOUT; ++o) acc += w[o] * att[o];
        alpha2[i * 32 + cc] = acc;
    }
}

// ---------------- fused prep B: split_x | splitW1T | splitW2T | splitLw1 | splitA1T ----------------
#define PB_X   2500
#define PB_W1  (PB_X + 128)
#define PB_W2  (PB_W1 + 32)
#define PB_LW  (PB_W2 + 128)
#define PB_A1  (PB_LW + 128)
__global__ void prep_b_kernel(const float* __restrict__ x, unsigned short* __restrict__ xhi,
                              unsigned short* __restrict__ xlo,
                              const float* __restrict__ W1, unsigned short* __restrict__ W1Thi,
                              const float* __restrict__ W2, unsigned short* __restrict__ W2Thi,
                              const float* __restrict__ lw1, unsigned short* __restrict__ Lhi,
                              unsigned short* __restrict__ Llo,
                              const float* __restrict__ alpha1, unsigned short* __restrict__ A1Thi,
                              unsigned short* __restrict__ A1Tlo) {
    __shared__ float T[128 * 65];
    int bb = blockIdx.x;
    int tid = threadIdx.x;
    if (bb < PB_X) {
        int g = bb * 256 + tid;
        if (g >= NN * DIN / 4) return;
        float4 v = ((const float4*)x)[g];
        ushort4 h, l;
        h.x = f2bf(v.x); l.x = f2bf(v.x - bf2f(h.x));
        h.y = f2bf(v.y); l.y = f2bf(v.y - bf2f(h.y));
        h.z = f2bf(v.z); l.z = f2bf(v.z - bf2f(h.z));
        h.w = f2bf(v.w); l.w = f2bf(v.w - bf2f(h.w));
        ((ushort4*)xhi)[g] = h;
        ((ushort4*)xlo)[g] = l;
    } else if (bb < PB_W1) {
        int blk = bb - PB_X;
        int r = blk >> 3, ob = blk & 7;
        for (int idx = tid; idx < 128 * 64; idx += 256) {
            int i = idx >> 6, o = idx & 63;
            T[i * 65 + o] = W1[((size_t)(r * DIN + i)) * DH + ob * 64 + o];
        }
        __syncthreads();
        for (int idx = tid; idx < 64 * 128; idx += 256) {
            int o = idx >> 7, i = idx & 127;
            W1Thi[((size_t)r * DH + ob * 64 + o) * DIN + i] = f2bf(T[i * 65 + o]);
        }
    } else if (bb < PB_W2) {
        int blk = bb - PB_W1;
        int r = blk >> 1, ob = blk & 1;
        for (int kc = 0; kc < 4; ++kc) {
            if (kc) __syncthreads();
            for (int idx = tid; idx < 128 * 64; idx += 256) {
                int k = idx >> 6, o = idx & 63;
                T[k * 65 + o] = W2[((size_t)(r * DH + kc * 128 + k)) * DOUT + ob * 64 + o];
            }
            __syncthreads();
            for (int idx = tid; idx < 64 * 128; idx += 256) {
                int o = idx >> 7, k = idx & 127;
                W2Thi[((size_t)r * DOUT + ob * 64 + o) * DH + kc * 128 + k] = f2bf(T[k * 65 + o]);
            }
        }
    } else if (bb < PB_LW) {
        int g = (bb - PB_W2) * 256 + tid;
        if (g >= 256 * 128) return;
        int o = g >> 8, k = g & 255;
        float v = lw1[k * 128 + o];
        unsigned short h = f2bf(v);
        Lhi[(size_t)o * 256 + k] = h;
        Llo[(size_t)o * 256 + k] = f2bf(v - bf2f(h));
    } else {
        int g = (bb - PB_LW) * 256 + tid;
        if (g >= 128 * 256) return;
        int c = g >> 7, i = g & 127;
        float v = alpha1[i * 256 + c];
        unsigned short h = f2bf(v);
        A1Thi[g] = h;
        A1Tlo[g] = f2bf(v - bf2f(h));
    }
}

// ---------------- sorts ----------------
__global__ void hist_kernel(const int* __restrict__ ei, const int* __restrict__ et,
                            int* __restrict__ cnt, int* __restrict__ cnt_d) {
    __shared__ int bins[NBUCKET];
    int t = threadIdx.x;
    if (t < NBUCKET) bins[t] = 0;
    __syncthreads();
    int e = blockIdx.x * 256 + t;
    if (e < NE) {
        int d = ei[NE + e];
        int key = (d / CHD) * NR + et[e];
        atomicAdd(&bins[key], 1);
        atomicAdd(&cnt_d[d], 1);
    }
    __syncthreads();
    if (t < NBUCKET && bins[t]) atomicAdd(&cnt[t], bins[t]);
}

// fused: block 0 = bucket scan (thread 0), block 1 = dst scan (1024 threads)
__global__ void scan_fused_kernel(const int* __restrict__ cnt, int* __restrict__ boffs,
                                  int* __restrict__ cursor, int* __restrict__ cts,
                                  const int* __restrict__ cnt_d, int* __restrict__ doffs,
                                  int* __restrict__ cursor_d) {
    __shared__ int part[1024];
    int t = threadIdx.x;
    if (blockIdx.x == 0) {
        if (t != 0) return;
        int acc = 0, tiles = 0;
        for (int b = 0; b < NBUCKET; ++b) {
            if ((b & (NR - 1)) == 0) cts[b >> 4] = tiles;
            boffs[b] = acc; cursor[b] = acc;
            int cn = cnt[b];
            tiles += (cn + TILE1 - 1) / TILE1;
            acc += cn;
        }
        boffs[NBUCKET] = acc; cts[CHUNKS] = tiles;
    } else {
        int base = t * 20;
        int s = 0;
        for (int i = 0; i < 20 && base + i < NN; ++i) s += cnt_d[base + i];
        part[t] = s;
        __syncthreads();
        for (int off = 1; off < 1024; off <<= 1) {
            int v = (t >= off) ? part[t - off] : 0;
            __syncthreads();
            part[t] += v;
            __syncthreads();
        }
        int run = part[t] - s;
        for (int i = 0; i < 20 && base + i < NN; ++i) {
            doffs[base + i] = run; cursor_d[base + i] = run;
            run += cnt_d[base + i];
        }
        if (t == 1023) doffs[NN] = part[1023];
    }
}

// fused: blocks [0,TMGRID) = tilemap; rest = bucket_place
__global__ void tmbp_kernel(const int* __restrict__ boffs, int* __restrict__ tile_b,
                            int* __restrict__ tile_s, const int* __restrict__ ei,
                            const int* __restrict__ et, int* __restrict__ cursor,
                            int* __restrict__ border) {
    int tid = threadIdx.x;
    if (blockIdx.x < TMGRID) {
        __shared__ int bo[NBUCKET + 1];
        if (tid <= NBUCKET) bo[tid] = boffs[tid];
        __syncthreads();
        int t = blockIdx.x * 256 + tid;
        if (t >= NTILESMAX1) return;
        int acc = 0, bb = -1, ss = 0;
        for (int b = 0; b < NBUCKET; ++b) {
            int cn = bo[b + 1] - bo[b];
            int nt = (cn + TILE1 - 1) / TILE1;
            if (t >= acc && t < acc + nt) { bb = b; ss = bo[b] + (t - acc) * TILE1; }
            acc += nt;
        }
        tile_b[t] = bb; tile_s[t] = ss;
    } else {
        __shared__ int binc[NBUCKET], base_[NBUCKET], rank_[NBUCKET];
        if (tid < NBUCKET) { binc[tid] = 0; rank_[tid] = 0; }
        __syncthreads();
        int e = (blockIdx.x - TMGRID) * 256 + tid;
        int key = -1;
        if (e < NE) { key = (ei[NE + e] / CHD) * NR + et[e]; atomicAdd(&binc[key], 1); }
        __syncthreads();
        if (tid < NBUCKET && binc[tid]) base_[tid] = atomicAdd(&cursor[tid], binc[tid]);
        __syncthreads();
        if (key >= 0) border[base_[key] + atomicAdd(&rank_[key], 1)] = e;
    }
}

__global__ void place_dst_kernel(const int* __restrict__ border, const int* __restrict__ ei,
                                 const int* __restrict__ et, int* __restrict__ cursor_d,
                                 int* __restrict__ dlist, int* __restrict__ dedge,
                                 int* __restrict__ dsr) {
    int pos = blockIdx.x * 256 + threadIdx.x;
    if (pos >= NE) return;
    int e = border[pos];
    int d = ei[NE + e];
    int idx = atomicAdd(&cursor_d[d], 1);
    dlist[idx] = pos;
    dedge[idx] = e;
    dsr[idx] = ei[e] * NR + et[e];
}

// ---------------- qk1 = x @ alpha1 (MFMA, 3-term split bf16; full precision) ----------------
__global__ __launch_bounds__(256, 2)
void qk1_mfma_kernel(const unsigned short* __restrict__ xhi, const unsigned short* __restrict__ xlo,
                     const unsigned short* __restrict__ A1Thi, const unsigned short* __restrict__ A1Tlo,
                     float* __restrict__ qk1) {
    int t = (blockIdx.x & 7) * (QGRID / 8) + (blockIdx.x >> 3);
    if (t >= MT2Y * 2) return;
    int mt = t >> 1, nb = t & 1;
    int n0 = mt * 128;
    __shared__ __align__(16) unsigned short Ah[128 * 64];
    __shared__ __align__(16) unsigned short Al[128 * 64];
    __shared__ __align__(16) unsigned short Bh_[128 * 64];
    __shared__ __align__(16) unsigned short Bl_[128 * 64];
    int tid = threadIdx.x;
    int w = tid >> 6, lane = tid & 63;
    int l15 = lane & 15, l4 = lane >> 4;
    int wr = w >> 1, wc = w & 1;
    f32x4 acc[4][4];
    #pragma unroll
    for (int m = 0; m < 4; ++m)
        #pragma unroll
        for (int n = 0; n < 4; ++n) acc[m][n] = (f32x4){0.f, 0.f, 0.f, 0.f};
    for (int kc = 0; kc < 2; ++kc) {
        if (kc) __syncthreads();
        {
            int row = tid >> 1, seg = tid & 1;
            int n = n0 + row; if (n >= NN) n = NN - 1;
            unsigned rb = row * 128, sw = (row & 7) << 4;
            const uint4* ph = (const uint4*)(xhi + (size_t)n * DIN + kc * 64 + seg * 32);
            const uint4* pl = (const uint4*)(xlo + (size_t)n * DIN + kc * 64 + seg * 32);
            const uint4* qh = (const uint4*)(A1Thi + (size_t)(nb * 128 + row) * DIN + kc * 64 + seg * 32);
            const uint4* ql = (const uint4*)(A1Tlo + (size_t)(nb * 128 + row) * DIN + kc * 64 + seg * 32);
            #pragma unroll
            for (int i = 0; i < 4; ++i) {
                unsigned off = (rb + seg * 64 + i * 16) ^ sw;
                *(uint4*)((char*)Ah + off) = ph[i];
                *(uint4*)((char*)Al + off) = pl[i];
                *(uint4*)((char*)Bh_ + off) = qh[i];
                *(uint4*)((char*)Bl_ + off) = ql[i];
            }
        }
        __syncthreads();
        bf16x8 ah[4][2], al[4][2], bh[4][2], bl[4][2];
        #pragma unroll
        for (int m = 0; m < 4; ++m) {
            int row = wr * 64 + m * 16 + l15;
            unsigned rb = row * 128, sw = (row & 7) << 4;
            #pragma unroll
            for (int ks = 0; ks < 2; ++ks) {
                unsigned off = (rb + ks * 64 + l4 * 16) ^ sw;
                ah[m][ks] = *(const bf16x8*)((const char*)Ah + off);
                al[m][ks] = *(const bf16x8*)((const char*)Al + off);
            }
        }
        #pragma unroll
        for (int n = 0; n < 4; ++n) {
            int col = wc * 64 + n * 16 + l15;
            unsigned rb = col * 128, sw = (col & 7) << 4;
            #pragma unroll
            for (int ks = 0; ks < 2; ++ks) {
                unsigned off = (rb + ks * 64 + l4 * 16) ^ sw;
                bh[n][ks] = *(const bf16x8*)((const char*)Bh_ + off);
                bl[n][ks] = *(const bf16x8*)((const char*)Bl_ + off);
            }
        }
        #pragma unroll
        for (int n = 0; n < 4; ++n)
            #pragma unroll
            for (int ks = 0; ks < 2; ++ks)
                #pragma unroll
                for (int m = 0; m < 4; ++m) {
                    acc[m][n] = __builtin_amdgcn_mfma_f32_16x16x32_bf16(ah[m][ks], bh[n][ks], acc[m][n], 0, 0, 0);
                    acc[m][n] = __builtin_amdgcn_mfma_f32_16x16x32_bf16(al[m][ks], bh[n][ks], acc[m][n], 0, 0, 0);
                    acc[m][n] = __builtin_amdgcn_mfma_f32_16x16x32_bf16(ah[m][ks], bl[n][ks], acc[m][n], 0, 0, 0);
                }
    }
    #pragma unroll
    for (int m = 0; m < 4; ++m) {
        int row0 = n0 + wr * 64 + m * 16 + l4 * 4;
        #pragma unroll
        for (int rg = 0; rg < 4; ++rg) {
            int row = row0 + rg;
            if (row < NN) {
                float* op = qk1 + (size_t)row * 256 + nb * 128 + wc * 64 + l15;
                #pragma unroll
                for (int n = 0; n < 4; ++n) op[n * 16] = acc[m][n][rg];
            }
        }
    }
}

// elogit1 in dst-sorted position order: writes e1s[idx*8+h]
__global__ void elogit1_kernel(const int* __restrict__ dedge, const int* __restrict__ ei,
                               const int* __restrict__ et, const float* __restrict__ qk1,
                               float* __restrict__ e1s) {
    int idx = blockIdx.x * blockDim.x + threadIdx.x;
    if (idx >= NE) return;
    int e = dedge[idx];
    int src = ei[e], dst = ei[NE + e], r = et[e];
    const float* qp = qk1 + (size_t)dst * 256 + r * 16;
    const float* kp = qk1 + (size_t)src * 256 + r * 16 + 8;
    float* ep = e1s + (size_t)idx * 8;
    #pragma unroll
    for (int h = 0; h < 8; ++h) {
        float l = qp[h] + kp[h];
        l = l > 0.f ? l : 0.2f * l;
        ep[h] = __expf(l);
    }
}

// ---------------- layer1 GEMM: 128x128 tiles, pure bf16 ----------------
__global__ __launch_bounds__(256, 4)
void l1_gemm_kernel(const unsigned short* __restrict__ xhi,
                    const unsigned short* __restrict__ W1Thi,
                    const int* __restrict__ ei, const int* __restrict__ border,
                    const int* __restrict__ tile_b, const int* __restrict__ tile_s,
                    const int* __restrict__ boffs, const int* __restrict__ cts,
                    int c, unsigned* __restrict__ msgu) {
    int wg = (blockIdx.x & 7) * (MAXTPC1 / 8) + (blockIdx.x >> 3);
    int tt = wg >> 2, cb = wg & 3;
    int t = cts[c] + tt;
    if (t >= cts[c + 1]) return;
    int b = tile_b[t];
    int r = b & (NR - 1);
    int start = tile_s[t];
    int cstart = boffs[c * NR];
    int cnt = boffs[b + 1] - start; if (cnt > TILE1) cnt = TILE1;
    __shared__ __align__(16) unsigned short Ah[128 * 64];
    __shared__ __align__(16) unsigned short Bh_[128 * 64];
    __shared__ int srcS[TILE1];
    int tid = threadIdx.x;
    if (tid < TILE1) {
        int sv = 0;
        if (tid < cnt) sv = ei[border[start + tid]];
        srcS[tid] = sv;
    }
    __syncthreads();
    int w = tid >> 6, lane = tid & 63;
    int l15 = lane & 15, l4 = lane >> 4;
    int wr = w >> 1, wc = w & 1;
    f32x4 acc[4][4];
    #pragma unroll
    for (int m = 0; m < 4; ++m)
        #pragma unroll
        for (int n = 0; n < 4; ++n) acc[m][n] = (f32x4){0.f, 0.f, 0.f, 0.f};
    for (int kc = 0; kc < 2; ++kc) {
        if (kc) __syncthreads();
        {
            int row = tid >> 1, seg = tid & 1;
            unsigned rb = row * 128, sw = (row & 7) << 4;
            const uint4* ph = (const uint4*)(xhi + (size_t)srcS[row] * DIN + kc * 64 + seg * 32);
            const uint4* qh = (const uint4*)(W1Thi + ((size_t)r * DH + cb * 128 + row) * DIN + kc * 64 + seg * 32);
            #pragma unroll
            for (int i = 0; i < 4; ++i) {
                unsigned off = (rb + seg * 64 + i * 16) ^ sw;
                *(uint4*)((char*)Ah + off) = ph[i];
                *(uint4*)((char*)Bh_ + off) = qh[i];
            }
        }
        __syncthreads();
        bf16x8 ah[4][2], bh[4][2];
        #pragma unroll
        for (int m = 0; m < 4; ++m) {
            int row = wr * 64 + m * 16 + l15;
            unsigned rb = row * 128, sw = (row & 7) << 4;
            #pragma unroll
            for (int ks = 0; ks < 2; ++ks) {
                unsigned off = (rb + ks * 64 + l4 * 16) ^ sw;
                ah[m][ks] = *(const bf16x8*)((const char*)Ah + off);
            }
        }
        #pragma unroll
        for (int n = 0; n < 4; ++n) {
            int col = wc * 64 + n * 16 + l15;
            unsigned rb = col * 128, sw = (col & 7) << 4;
            #pragma unroll
            for (int ks = 0; ks < 2; ++ks) {
                unsigned off = (rb + ks * 64 + l4 * 16) ^ sw;
                bh[n][ks] = *(const bf16x8*)((const char*)Bh_ + off);
            }
        }
        #pragma unroll
        for (int n = 0; n < 4; ++n)
            #pragma unroll
            for (int ks = 0; ks < 2; ++ks)
                #pragma unroll
                for (int m = 0; m < 4; ++m)
                    acc[m][n] = __builtin_amdgcn_mfma_f32_16x16x32_bf16(ah[m][ks], bh[n][ks], acc[m][n], 0, 0, 0);
    }
    unsigned* mb = msgu + (size_t)(start - cstart) * 256 + cb * 64 + wc * 32 + l15;
    #pragma unroll
    for (int m = 0; m < 4; ++m) {
        int row0 = wr * 64 + m * 16 + l4 * 4;
        #pragma unroll
        for (int rg = 0; rg < 4; ++rg) {
            int row = row0 + rg;
            if (row < cnt) {
                unsigned* mp = mb + (size_t)row * 256;
                mp[0]  = packbf(acc[m][0][rg], acc[m][2][rg]);
                mp[16] = packbf(acc[m][1][rg], acc[m][3][rg]);
            }
        }
    }
}

// ---------------- layer1 agg (fused qk2): position-ordered weights, unroll 4 ----------------
__global__ void l1_agg_kernel(const unsigned* __restrict__ msgu, const float* __restrict__ e1s,
                              const int* __restrict__ dlist,
                              const int* __restrict__ doffs, const int* __restrict__ boffs,
                              int c, unsigned short* __restrict__ hhi,
                              const float* __restrict__ alpha2, float* __restrict__ qk2v) {
    __shared__ float hrow[DH];
    __shared__ float red[32][9];
    int tid = threadIdx.x;
    int d = c * CHD + blockIdx.x;
    if (d >= NN) return;
    int lo_ = doffs[d], hi_ = doffs[d + 1];
    int cstart = boffs[c * NR];
    int head = tid >> 5;
    float a0 = 0.f, a1 = 0.f, se = 0.f;
    int p = lo_;
    for (; p + 3 < hi_; p += 4) {
        int pos0 = dlist[p], pos1 = dlist[p + 1], pos2 = dlist[p + 2], pos3 = dlist[p + 3];
        float w0 = e1s[(size_t)p * 8 + head];
        float w1 = e1s[(size_t)(p + 1) * 8 + head];
        float w2 = e1s[(size_t)(p + 2) * 8 + head];
        float w3 = e1s[(size_t)(p + 3) * 8 + head];
        unsigned v0 = msgu[(size_t)(pos0 - cstart) * 256 + tid];
        unsigned v1 = msgu[(size_t)(pos1 - cstart) * 256 + tid];
        unsigned v2 = msgu[(size_t)(pos2 - cstart) * 256 + tid];
        unsigned v3 = msgu[(size_t)(pos3 - cstart) * 256 + tid];
        se += (w0 + w1) + (w2 + w3);
        a0 += w0 * bf2f((unsigned short)(v0 & 0xffff)) + w1 * bf2f((unsigned short)(v1 & 0xffff))
            + w2 * bf2f((unsigned short)(v2 & 0xffff)) + w3 * bf2f((unsigned short)(v3 & 0xffff));
        a1 += w0 * bf2f((unsigned short)(v0 >> 16)) + w1 * bf2f((unsigned short)(v1 >> 16))
            + w2 * bf2f((unsigned short)(v2 >> 16)) + w3 * bf2f((unsigned short)(v3 >> 16));
    }
    for (; p < hi_; ++p) {
        int pos0 = dlist[p];
        float w0 = e1s[(size_t)p * 8 + head];
        unsigned v0 = msgu[(size_t)(pos0 - cstart) * 256 + tid];
        se += w0;
        a0 += w0 * bf2f((unsigned short)(v0 & 0xffff));
        a1 += w0 * bf2f((unsigned short)(v0 >> 16));
    }
    float inv = 1.f / (se + 1e-16f);
    a0 *= inv; a1 *= inv;
    a0 = a0 > 0.f ? a0 : 0.f;
    a1 = a1 > 0.f ? a1 : 0.f;
    int w = tid >> 6, q = (tid >> 4) & 3, l15 = tid & 15;
    int nq = ((q >> 1) << 2) | (q & 1);
    int c0 = w * 128 + nq * 16 + l15;
    hrow[c0] = a0; hrow[c0 + 32] = a1;
    hhi[(size_t)d * DH + c0] = f2bf(a0);
    hhi[(size_t)d * DH + c0 + 32] = f2bf(a1);
    __syncthreads();
    int j = tid & 31, ib = tid >> 5;
    float s = 0.f;
    #pragma unroll 8
    for (int i = ib * 64; i < ib * 64 + 64; ++i) s += hrow[i] * alpha2[(size_t)i * 32 + j];
    red[j][ib] = s;
    __syncthreads();
    if (tid < 32) {
        float t = 0.f;
        #pragma unroll
        for (int g = 0; g < 8; ++g) t += red[tid][g];
        qk2v[(size_t)d * 32 + tid] = t;
    }
}

// elogit2 in dst-sorted position order: writes e2s[idx]
__global__ void elogit2_kernel(const int* __restrict__ dedge, const int* __restrict__ ei,
                               const int* __restrict__ et, const float* __restrict__ qk2,
                               float* __restrict__ e2s) {
    int idx = blockIdx.x * blockDim.x + threadIdx.x;
    if (idx >= NE) return;
    int e = dedge[idx];
    int src = ei[e], dst = ei[NE + e], r = et[e];
    float l = qk2[(size_t)dst * 32 + r * 2] + qk2[(size_t)src * 32 + r * 2 + 1];
    l = l > 0.f ? l : 0.2f * l;
    e2s[idx] = __expf(l);
}

// ---------------- dense Y2 = H @ W2_all : pure bf16 ----------------
__global__ __launch_bounds__(256, 4)
void y2_gemm_kernel(const unsigned short* __restrict__ hhi,
                    const unsigned short* __restrict__ W2Thi,
                    unsigned* __restrict__ Y2u) {
    int t = (blockIdx.x & 7) * (YGRID / 8) + (blockIdx.x >> 3);
    int mt = t >> 4, r = t & 15;
    int n0 = mt * 128;
    __shared__ __align__(16) unsigned short Ah[128 * 64];
    __shared__ __align__(16) unsigned short Bh_[128 * 64];
    int tid = threadIdx.x;
    int w = tid >> 6, lane = tid & 63;
    int l15 = lane & 15, l4 = lane >> 4;
    int wr = w >> 1, wc = w & 1;
    f32x4 acc[4][4];
    #pragma unroll
    for (int m = 0; m < 4; ++m)
        #pragma unroll
        for (int n = 0; n < 4; ++n) acc[m][n] = (f32x4){0.f, 0.f, 0.f, 0.f};
    for (int kc = 0; kc < 8; ++kc) {
        if (kc) __syncthreads();
        {
            int row = tid >> 1, seg = tid & 1;
            int n = n0 + row; if (n >= NN) n = NN - 1;
            unsigned rb = row * 128, sw = (row & 7) << 4;
            const uint4* ph = (const uint4*)(hhi + (size_t)n * DH + kc * 64 + seg * 32);
            const uint4* qh = (const uint4*)(W2Thi + ((size_t)r * DOUT + row) * DH + kc * 64 + seg * 32);
            #pragma unroll
            for (int i = 0; i < 4; ++i) {
                unsigned off = (rb + seg * 64 + i * 16) ^ sw;
                *(uint4*)((char*)Ah + off) = ph[i];
                *(uint4*)((char*)Bh_ + off) = qh[i];
            }
        }
        __syncthreads();
        bf16x8 ah[4][2], bh[4][2];
        #pragma unroll
        for (int m = 0; m < 4; ++m) {
            int row = wr * 64 + m * 16 + l15;
            unsigned rb = row * 128, sw = (row & 7) << 4;
            #pragma unroll
            for (int ks = 0; ks < 2; ++ks) {
                unsigned off = (rb + ks * 64 + l4 * 16) ^ sw;
                ah[m][ks] = *(const bf16x8*)((const char*)Ah + off);
            }
        }
        #pragma unroll
        for (int n = 0; n < 4; ++n) {
            int col = wc * 64 + n * 16 + l15;
            unsigned rb = col * 128, sw = (col & 7) << 4;
            #pragma unroll
            for (int ks = 0; ks < 2; ++ks) {
                unsigned off = (rb + ks * 64 + l4 * 16) ^ sw;
                bh[n][ks] = *(const bf16x8*)((const char*)Bh_ + off);
            }
        }
        #pragma unroll
        for (int n = 0; n < 4; ++n)
            #pragma unroll
            for (int ks = 0; ks < 2; ++ks)
                #pragma unroll
                for (int m = 0; m < 4; ++m)
                    acc[m][n] = __builtin_amdgcn_mfma_f32_16x16x32_bf16(ah[m][ks], bh[n][ks], acc[m][n], 0, 0, 0);
    }
    unsigned* mb = Y2u + (size_t)n0 * 1024 + r * 64 + wc * 32 + l15;
    #pragma unroll
    for (int m = 0; m < 4; ++m) {
        int row0 = wr * 64 + m * 16 + l4 * 4;
        #pragma unroll
        for (int rg = 0; rg < 4; ++rg) {
            int row = row0 + rg;
            if (n0 + row < NN) {
                unsigned* mp = mb + (size_t)row * 1024;
                mp[0]  = packbf(acc[m][0][rg], acc[m][2][rg]);
                mp[16] = packbf(acc[m][1][rg], acc[m][3][rg]);
            }
        }
    }
}

// ---------------- layer2 agg: position-ordered weights, unroll 4 ----------------
__global__ void l2_agg_kernel(const unsigned* __restrict__ Y2u, const float* __restrict__ e2s,
                              const int* __restrict__ dsr,
                              const int* __restrict__ doffs, float* __restrict__ zacc) {
    int tid = threadIdx.x;
    int d = blockIdx.x * 4 + (tid >> 6);
    if (d >= NN) return;
    int lane = tid & 63;
    int lo_ = doffs[d], hi_ = doffs[d + 1];
    float a0 = 0.f, a1 = 0.f, se = 0.f;
    int p = lo_;
    for (; p + 3 < hi_; p += 4) {
        int s0 = dsr[p], s1 = dsr[p + 1], s2 = dsr[p + 2], s3 = dsr[p + 3];
        float w0 = e2s[p], w1 = e2s[p + 1], w2 = e2s[p + 2], w3 = e2s[p + 3];
        unsigned v0 = Y2u[(size_t)s0 * 64 + lane];
        unsigned v1 = Y2u[(size_t)s1 * 64 + lane];
        unsigned v2 = Y2u[(size_t)s2 * 64 + lane];
        unsigned v3 = Y2u[(size_t)s3 * 64 + lane];
        se += (w0 + w1) + (w2 + w3);
        a0 += w0 * bf2f((unsigned short)(v0 & 0xffff)) + w1 * bf2f((unsigned short)(v1 & 0xffff))
            + w2 * bf2f((unsigned short)(v2 & 0xffff)) + w3 * bf2f((unsigned short)(v3 & 0xffff));
        a1 += w0 * bf2f((unsigned short)(v0 >> 16)) + w1 * bf2f((unsigned short)(v1 >> 16))
            + w2 * bf2f((unsigned short)(v2 >> 16)) + w3 * bf2f((unsigned short)(v3 >> 16));
    }
    for (; p < hi_; ++p) {
        float w0 = e2s[p];
        unsigned v0 = Y2u[(size_t)dsr[p] * 64 + lane];
        se += w0;
        a0 += w0 * bf2f((unsigned short)(v0 & 0xffff));
        a1 += w0 * bf2f((unsigned short)(v0 >> 16));
    }
    float inv = 1.f / (se + 1e-16f);
    int q = lane >> 4, l15 = lane & 15;
    int nq = ((q >> 1) << 2) | (q & 1);
    int c0 = nq * 16 + l15;
    zacc[(size_t)d * DOUT + c0] = a0 * inv;
    zacc[(size_t)d * DOUT + c0 + 32] = a1 * inv;
}

// ---------------- link-prediction decoder (MFMA, split bf16, full 3-term) ----------------
__global__ __launch_bounds__(256, 2)
void decode_kernel(const float* __restrict__ z, const int* __restrict__ tgt,
                   const unsigned short* __restrict__ Lhi, const unsigned short* __restrict__ Llo,
                   const float* __restrict__ lb1, const float* __restrict__ lw2,
                   const float* __restrict__ lb2, float* __restrict__ out) {
    __shared__ __align__(16) unsigned short Ah[64 * 256];
    __shared__ __align__(16) unsigned short Al[64 * 256];
    __shared__ float red[TILE][5];
    int t0 = blockIdx.x * TILE;
    int tid = threadIdx.x;
    int cnt = NT - t0; if (cnt > TILE) cnt = TILE;
    {
        int row = tid >> 2, seg = tid & 3;
        int node = 0;
        bool live = (row < cnt);
        if (live) node = tgt[(seg >> 1) * NT + t0 + row];
        const float4* pz = (const float4*)(z + (size_t)node * DOUT + (seg & 1) * 64);
        unsigned rb = row * 512, sb = (seg >> 1) * 256 + (seg & 1) * 128;
        unsigned sw = (row & 7) << 4;
        #pragma unroll
        for (int g = 0; g < 8; ++g) {
            float4 a = live ? pz[g * 2] : (float4){0,0,0,0};
            float4 bq = live ? pz[g * 2 + 1] : (float4){0,0,0,0};
            unsigned short h0 = f2bf(a.x), h1 = f2bf(a.y), h2 = f2bf(a.z), h3 = f2bf(a.w);
            unsigned short h4 = f2bf(bq.x), h5 = f2bf(bq.y), h6 = f2bf(bq.z), h7 = f2bf(bq.w);
            uint4 uh, ul;
            uh.x = (unsigned)h0 | ((unsigned)h1 << 16);
            uh.y = (unsigned)h2 | ((unsigned)h3 << 16);
            uh.z = (unsigned)h4 | ((unsigned)h5 << 16);
            uh.w = (unsigned)h6 | ((unsigned)h7 << 16);
            ul.x = (unsigned)f2bf(a.x - bf2f(h0)) | ((unsigned)f2bf(a.y - bf2f(h1)) << 16);
            ul.y = (unsigned)f2bf(a.z - bf2f(h2)) | ((unsigned)f2bf(a.w - bf2f(h3)) << 16);
            ul.z = (unsigned)f2bf(bq.x - bf2f(h4)) | ((unsigned)f2bf(bq.y - bf2f(h5)) << 16);
            ul.w = (unsigned)f2bf(bq.z - bf2f(h6)) | ((unsigned)f2bf(bq.w - bf2f(h7)) << 16);
            unsigned off = (rb + sb + g * 16) ^ sw;
            *(uint4*)((char*)Ah + off) = uh;
            *(uint4*)((char*)Al + off) = ul;
        }
    }
    __syncthreads();
    int w = tid >> 6, lane = tid & 63;
    int l15 = lane & 15, l4 = lane >> 4;
    const unsigned short* Bh = Lhi + (size_t)(w * 32 + l15) * 256 + l4 * 8;
    const unsigned short* Bl = Llo + (size_t)(w * 32 + l15) * 256 + l4 * 8;
    f32x4 acc[4][2];
    #pragma unroll
    for (int m = 0; m < 4; ++m) { acc[m][0] = (f32x4){0.f,0.f,0.f,0.f}; acc[m][1] = (f32x4){0.f,0.f,0.f,0.f}; }
    #pragma unroll
    for (int k = 0; k < 8; ++k) {
        bf16x8 ah[4], al[4];
        #pragma unroll
        for (int m = 0; m < 4; ++m) {
            int row = m * 16 + l15;
            unsigned off = ((unsigned)row * 512 + k * 64 + l4 * 16) ^ ((unsigned)(row & 7) << 4);
            ah[m] = *(const bf16x8*)((const char*)Ah + off);
            al[m] = *(const bf16x8*)((const char*)Al + off);
        }
        #pragma unroll
        for (int n = 0; n < 2; ++n) {
            bf16x8 bh = *(const bf16x8*)(Bh + (size_t)n * 16 * 256 + k * 32);
            bf16x8 bl = *(const bf16x8*)(Bl + (size_t)n * 16 * 256 + k * 32);
            #pragma unroll
            for (int m = 0; m < 4; ++m) {
                acc[m][n] = __builtin_amdgcn_mfma_f32_16x16x32_bf16(ah[m], bh, acc[m][n], 0, 0, 0);
                acc[m][n] = __builtin_amdgcn_mfma_f32_16x16x32_bf16(ah[m], bl, acc[m][n], 0, 0, 0);
                acc[m][n] = __builtin_amdgcn_mfma_f32_16x16x32_bf16(al[m], bh, acc[m][n], 0, 0, 0);
            }
        }
    }
    int col0 = w * 32 + l15;
    float lb_0 = lb1[col0], lb_1 = lb1[col0 + 16];
    float lwa = lw2[col0], lwb = lw2[col0 + 16];
    #pragma unroll
    for (int m = 0; m < 4; ++m) {
        #pragma unroll
        for (int rg = 0; rg < 4; ++rg) {
            float h0 = acc[m][0][rg] + lb_0; h0 = h0 > 0.f ? h0 : 0.f;
            float h1 = acc[m][1][rg] + lb_1; h1 = h1 > 0.f ? h1 : 0.f;
            float s = h0 * lwa + h1 * lwb;
            s += __shfl_xor(s, 1); s += __shfl_xor(s, 2);
            s += __shfl_xor(s, 4); s += __shfl_xor(s, 8);
            if (l15 == 0) red[m * 16 + l4 * 4 + rg][w] = s;
        }
    }
    __syncthreads();
    if (tid < cnt) out[t0 + tid] = red[tid][0] + red[tid][1] + red[tid][2] + red[tid][3] + lb2[0];
}

extern "C" void kernel_launch(void* const* d_in, const int* in_sizes, int n_in,
                              void* d_out, int out_size, void* d_ws, size_t ws_size,
                              hipStream_t stream) {
    const float* x   = (const float*)d_in[0];
    const int*   ei  = (const int*)d_in[1];
    const int*   et  = (const int*)d_in[2];
    const int*   tgt = (const int*)d_in[3];
    const float* W1  = (const float*)d_in[4];
    const float* aq1 = (const float*)d_in[5];
    const float* ak1 = (const float*)d_in[6];
    const float* W2  = (const float*)d_in[7];
    const float* aq2 = (const float*)d_in[8];
    const float* ak2 = (const float*)d_in[9];
    const float* lw1 = (const float*)d_in[10];
    const float* lb1 = (const float*)d_in[11];
    const float* lw2 = (const float*)d_in[12];
    const float* lb2 = (const float*)d_in[13];
    float* out = (float*)d_out;
    (void)in_sizes; (void)n_in; (void)out_size; (void)ws_size;

    char* ws = (char*)d_ws;
    size_t off = 0;
    auto alloc = [&](size_t bytes) -> void* {
        void* p = ws + off;
        off += (bytes + 255) & ~(size_t)255;
        return p;
    };
    // zero-init block: histograms only
    int* cnt   = (int*)alloc(NBUCKET * sizeof(int));
    int* cnt_d = (int*)alloc((size_t)NN * sizeof(int));
    size_t zero_bytes = off;
    // no-init scratch
    int*   boffs    = (int*)alloc((NBUCKET + 1) * sizeof(int));
    int*   cursor   = (int*)alloc(NBUCKET * sizeof(int));
    int*   cts      = (int*)alloc((CHUNKS + 1) * sizeof(int));
    int*   doffs    = (int*)alloc((size_t)(NN + 1) * sizeof(int));
    int*   cursor_d = (int*)alloc((size_t)NN * sizeof(int));
    int*   border   = (int*)alloc((size_t)NE * sizeof(int));
    int*   dlist    = (int*)alloc((size_t)NE * sizeof(int));
    int*   dedge    = (int*)alloc((size_t)NE * sizeof(int));
    int*   dsr      = (int*)alloc((size_t)NE * sizeof(int));
    int*   tile_b   = (int*)alloc((size_t)NTILESMAX1 * sizeof(int));
    int*   tile_s   = (int*)alloc((size_t)NTILESMAX1 * sizeof(int));
    float* alpha2   = (float*)alloc((size_t)512 * 32 * 4);
    float* qk2v     = (float*)alloc((size_t)NN * 32 * 4);
    float* e2s      = (float*)alloc((size_t)NE * 4);
    float* zacc     = (float*)alloc((size_t)NN * DOUT * 4);
    unsigned short* xhi   = (unsigned short*)alloc((size_t)NN * DIN * 2);
    unsigned short* xlo   = (unsigned short*)alloc((size_t)NN * DIN * 2);
    unsigned short* hhi   = (unsigned short*)alloc((size_t)NN * DH * 2);
    unsigned short* W1Thi = (unsigned short*)alloc((size_t)NR * DH * DIN * 2);
    unsigned short* W2Thi = (unsigned short*)alloc((size_t)NR * DOUT * DH * 2);
    unsigned short* Lhi   = (unsigned short*)alloc((size_t)128 * 256 * 2);
    unsigned short* Llo   = (unsigned short*)alloc((size_t)128 * 256 * 2);
    unsigned short* A1Thi = (unsigned short*)alloc((size_t)256 * 128 * 2);
    unsigned short* A1Tlo = (unsigned short*)alloc((size_t)256 * 128 * 2);
    // region R (82 MB): [alpha1|qk1] alias the head (dead before chunk-0 gemm);
    // msg occupies rows [0, MSGROWS); e1s sits at the fixed tail offset.
    // After the l1 loop the whole region is reused as the dense Y2 table.
    char* msgr = (char*)alloc((size_t)NN * 1024 * 4);               // 81,920,000 B
    unsigned* msgu = (unsigned*)msgr;
    unsigned* Y2u  = (unsigned*)msgr;
    float* alpha1 = (float*)msgr;                                   // 131,072 B
    float* qk1    = (float*)(msgr + 131072);                        // 20,480,000 B
    float* e1s    = (float*)(msgr + (size_t)MSGROWS * 1024);        // 10,240,000 B, ends 81.8 MB

    hipMemsetAsync(ws, 0, zero_bytes, stream);
    prep_a_kernel<<<192, 256, 0, stream>>>(W1, aq1, ak1, alpha1, W2, aq2, ak2, alpha2);
    prep_b_kernel<<<PB_A1 + 128, 256, 0, stream>>>(x, xhi, xlo, W1, W1Thi, W2, W2Thi,
                                                   lw1, Lhi, Llo, alpha1, A1Thi, A1Tlo);
    hist_kernel<<<(NE + 255) / 256, 256, 0, stream>>>(ei, et, cnt, cnt_d);
    scan_fused_kernel<<<2, 1024, 0, stream>>>(cnt, boffs, cursor, cts, cnt_d, doffs, cursor_d);
    tmbp_kernel<<<TMGRID + (NE + 255) / 256, 256, 0, stream>>>(boffs, tile_b, tile_s,
                                                               ei, et, cursor, border);
    place_dst_kernel<<<(NE + 255) / 256, 256, 0, stream>>>(border, ei, et, cursor_d, dlist, dedge, dsr);
    qk1_mfma_kernel<<<QGRID, 256, 0, stream>>>(xhi, xlo, A1Thi, A1Tlo, qk1);
    elogit1_kernel<<<(NE + 255) / 256, 256, 0, stream>>>(dedge, ei, et, qk1, e1s);
    for (int c = 0; c < CHUNKS; ++c) {
        l1_gemm_kernel<<<MAXTPC1, 256, 0, stream>>>(xhi, W1Thi, ei, border,
                                                    tile_b, tile_s, boffs, cts, c, msgu);
        l1_agg_kernel<<<CHD, 256, 0, stream>>>(msgu, e1s, dlist, doffs, boffs, c,
                                               hhi, alpha2, qk2v);
    }
    elogit2_kernel<<<(NE + 255) / 256, 256, 0, stream>>>(dedge, ei, et, qk2v, e2s);
    y2_gemm_kernel<<<YGRID, 256, 0, stream>>>(hhi, W2Thi, Y2u);
    l2_agg_kernel<<<(NN + 3) / 4, 256, 0, stream>>>(Y2u, e2s, dsr, doffs, zacc);
    decode_kernel<<<(NT + TILE - 1) / TILE, 256, 0, stream>>>(zacc, tgt, Lhi, Llo,
                                                              lb1, lw2, lb2, out);
}